// Round 1
// baseline (722.756 us; speedup 1.0000x reference)
//
#include <hip/hip_runtime.h>

// GraphFeatureTokenizer: B=8, HID=768, K=32, TOK=4, MAXLEN=15360
// Outputs concatenated flat (float32): feature [8,15360,768], mask [8,15360], index [8,15360,2]

constexpr int BGRAPH = 8;
constexpr int HID    = 768;
constexpr int MAXLEN = 15360;
constexpr int TB     = 32;   // tokens per block

__global__ __launch_bounds__(256)
void gft_kernel(const float* __restrict__ embedW,   // [50257,768]
                const float* __restrict__ lapW,     // [64,768]
                const float* __restrict__ orderW,   // [2,768]
                const float* __restrict__ eig,      // [N,32]
                const int*   __restrict__ node_data,// [N,4]
                const int*   __restrict__ edge_data,// [E,4]
                const int*   __restrict__ edge_index,// [2,E]
                const int*   __restrict__ node_num, // [8]
                const int*   __restrict__ edge_num, // [8]
                int E,
                float* __restrict__ outF,
                float* __restrict__ outM,
                float* __restrict__ outI)
{
    const int b   = blockIdx.y;
    const int t0  = blockIdx.x * TB;
    const int tid = threadIdx.x;

    // prefix sums over the 8 graphs (uniform scalar loads)
    int ns = 0, es = 0, nn = 0, en = 0;
    #pragma unroll
    for (int g = 0; g < BGRAPH; ++g) {
        int nv = node_num[g], ev = edge_num[g];
        if (g < b)  { ns += nv; es += ev; }
        if (g == b) { nn = nv;  en = ev; }
    }
    const int seq = nn + en;

    float* rowF = outF + ((size_t)b * MAXLEN + t0) * HID;

    if (t0 >= seq) {
        // whole tile is padding: zero feature, mask=1, index=0
        #pragma unroll 4
        for (int tok = 0; tok < TB; ++tok) {
            size_t off = (size_t)tok * HID;
            rowF[off + tid]       = 0.f;
            rowF[off + tid + 256] = 0.f;
            rowF[off + tid + 512] = 0.f;
        }
        if (tid < TB) {
            int t = t0 + tid;
            outM[b * MAXLEN + t] = 1.0f;
            outI[((size_t)b * MAXLEN + t) * 2 + 0] = 0.f;
            outI[((size_t)b * MAXLEN + t) * 2 + 1] = 0.f;
        }
        return;
    }

    __shared__ float sh_eig[64][TB];   // [j][tok], rows 128B -> float4 over tok ok
    __shared__ int   sh_ids[TB][4];
    __shared__ int   sh_i0[TB], sh_i1[TB], sh_gA[TB], sh_gB[TB];

    // ---- phase 0: token metadata (one thread per token) ----
    if (tid < TB) {
        int t = t0 + tid;
        int i0 = 0, i1 = 0, gA = -1, gB = -1;
        int id0 = 0, id1 = 0, id2 = 0, id3 = 0;
        if (t < seq) {
            if (t < nn) {               // node token
                int g = ns + t;
                i0 = t; i1 = t; gA = g; gB = g;
                id0 = node_data[g * 4 + 0];
                id1 = node_data[g * 4 + 1];
                id2 = node_data[g * 4 + 2];
                id3 = node_data[g * 4 + 3];
            } else {                    // edge token
                int ge = es + (t - nn);
                i0 = edge_index[ge];
                i1 = edge_index[E + ge];
                gA = ns + i0; gB = ns + i1;
                id0 = edge_data[ge * 4 + 0];
                id1 = edge_data[ge * 4 + 1];
                id2 = edge_data[ge * 4 + 2];
                id3 = edge_data[ge * 4 + 3];
            }
        }
        sh_i0[tid] = i0; sh_i1[tid] = i1;
        sh_gA[tid] = gA; sh_gB[tid] = gB;
        sh_ids[tid][0] = id0; sh_ids[tid][1] = id1;
        sh_ids[tid][2] = id2; sh_ids[tid][3] = id3;
    }
    __syncthreads();

    // ---- phase 1: stage eig pairs into LDS [j][tok] ----
    {
        int tok   = tid >> 3;           // 0..31
        int jbase = (tid & 7) * 8;      // 0..56
        int gA = sh_gA[tok], gB = sh_gB[tok];
        #pragma unroll
        for (int jj = 0; jj < 8; ++jj) {
            int j = jbase + jj;
            float v = 0.f;
            if (j < 32) { if (gA >= 0) v = eig[(size_t)gA * 32 + j]; }
            else        { if (gB >= 0) v = eig[(size_t)gB * 32 + (j - 32)]; }
            sh_eig[j][tok] = v;
        }
    }
    __syncthreads();

    // ---- phase 2: lap projection, acc[tok][s] for s = col slot {tid, tid+256, tid+512} ----
    float acc[TB * 3];
    #pragma unroll
    for (int i = 0; i < TB * 3; ++i) acc[i] = 0.f;

    const float* wc = lapW + tid;
    for (int j = 0; j < 64; ++j) {
        float w0 = wc[j * HID];
        float w1 = wc[j * HID + 256];
        float w2 = wc[j * HID + 512];
        const float4* ev = (const float4*)(&sh_eig[j][0]);
        #pragma unroll
        for (int q = 0; q < TB / 4; ++q) {
            float4 e4 = ev[q];
            acc[(q * 4 + 0) * 3 + 0] += e4.x * w0;
            acc[(q * 4 + 0) * 3 + 1] += e4.x * w1;
            acc[(q * 4 + 0) * 3 + 2] += e4.x * w2;
            acc[(q * 4 + 1) * 3 + 0] += e4.y * w0;
            acc[(q * 4 + 1) * 3 + 1] += e4.y * w1;
            acc[(q * 4 + 1) * 3 + 2] += e4.y * w2;
            acc[(q * 4 + 2) * 3 + 0] += e4.z * w0;
            acc[(q * 4 + 2) * 3 + 1] += e4.z * w1;
            acc[(q * 4 + 2) * 3 + 2] += e4.z * w2;
            acc[(q * 4 + 3) * 3 + 0] += e4.w * w0;
            acc[(q * 4 + 3) * 3 + 1] += e4.w * w1;
            acc[(q * 4 + 3) * 3 + 2] += e4.w * w2;
        }
    }

    // ---- phase 3: embedding gather-sum + order + store ----
    #pragma unroll
    for (int tok = 0; tok < TB; ++tok) {
        int t = t0 + tok;
        size_t off = (size_t)tok * HID;
        if (t >= seq) {
            rowF[off + tid]       = 0.f;
            rowF[off + tid + 256] = 0.f;
            rowF[off + tid + 512] = 0.f;
            continue;
        }
        float f0 = 0.f, f1 = 0.f, f2 = 0.f;
        #pragma unroll
        for (int r = 0; r < 4; ++r) {
            const float* e = embedW + (size_t)sh_ids[tok][r] * HID;
            f0 += e[tid];
            f1 += e[tid + 256];
            f2 += e[tid + 512];
        }
        int ord = (sh_i0[tok] == sh_i1[tok]) ? 1 : 0;
        const float* ow = orderW + (size_t)ord * HID;
        f0 += acc[tok * 3 + 0] + ow[tid];
        f1 += acc[tok * 3 + 1] + ow[tid + 256];
        f2 += acc[tok * 3 + 2] + ow[tid + 512];
        rowF[off + tid]       = f0;
        rowF[off + tid + 256] = f1;
        rowF[off + tid + 512] = f2;
    }

    if (tid < TB) {
        int t = t0 + tid;
        bool pad = (t >= seq);
        outM[b * MAXLEN + t] = pad ? 1.0f : 0.0f;
        outI[((size_t)b * MAXLEN + t) * 2 + 0] = pad ? 0.f : (float)sh_i0[tid];
        outI[((size_t)b * MAXLEN + t) * 2 + 1] = pad ? 0.f : (float)sh_i1[tid];
    }
}

extern "C" void kernel_launch(void* const* d_in, const int* in_sizes, int n_in,
                              void* d_out, int out_size, void* d_ws, size_t ws_size,
                              hipStream_t stream) {
    const float* embedW     = (const float*)d_in[0];
    const float* lapW       = (const float*)d_in[1];
    const float* orderW     = (const float*)d_in[2];
    const float* eig        = (const float*)d_in[3];
    const int*   node_data  = (const int*)d_in[4];
    const int*   edge_data  = (const int*)d_in[5];
    const int*   edge_index = (const int*)d_in[6];
    const int*   node_num   = (const int*)d_in[7];
    const int*   edge_num   = (const int*)d_in[8];
    const int E = in_sizes[6] / 2;

    float* outF = (float*)d_out;
    float* outM = outF + (size_t)BGRAPH * MAXLEN * HID;
    float* outI = outM + (size_t)BGRAPH * MAXLEN;

    dim3 grid(MAXLEN / TB, BGRAPH);
    gft_kernel<<<grid, 256, 0, stream>>>(embedW, lapW, orderW, eig,
                                         node_data, edge_data, edge_index,
                                         node_num, edge_num, E,
                                         outF, outM, outI);
}

// Round 2
// 658.278 us; speedup vs baseline: 1.0980x; 1.0980x over previous
//
#include <hip/hip_runtime.h>

// GraphFeatureTokenizer: B=8, HID=768, K=32, TOK=4, MAXLEN=15360
// Outputs concatenated flat (float32): feature [8,15360,768], mask [8,15360], index [8,15360,2]

constexpr int BGRAPH = 8;
constexpr int HID    = 768;
constexpr int MAXLEN = 15360;
constexpr int TB     = 16;    // tokens per block
constexpr int BLOCK  = 192;   // 192 threads * float4 = 768 cols

__global__ __launch_bounds__(BLOCK)
void gft_kernel(const float* __restrict__ embedW,   // [50257,768]
                const float* __restrict__ lapW,     // [64,768]
                const float* __restrict__ orderW,   // [2,768]
                const float* __restrict__ eig,      // [N,32]
                const int*   __restrict__ node_data,// [N,4]
                const int*   __restrict__ edge_data,// [E,4]
                const int*   __restrict__ edge_index,// [2,E]
                const int*   __restrict__ node_num, // [8]
                const int*   __restrict__ edge_num, // [8]
                int E,
                float* __restrict__ outF,
                float* __restrict__ outM,
                float* __restrict__ outI)
{
    const int b   = blockIdx.y;
    const int t0  = blockIdx.x * TB;
    const int tid = threadIdx.x;

    // prefix sums over the 8 graphs (uniform scalar loads)
    int ns = 0, es = 0, nn = 0, en = 0;
    #pragma unroll
    for (int g = 0; g < BGRAPH; ++g) {
        int nv = node_num[g], ev = edge_num[g];
        if (g < b)  { ns += nv; es += ev; }
        if (g == b) { nn = nv;  en = ev; }
    }
    const int seq = nn + en;

    float* rowF = outF + ((size_t)b * MAXLEN + t0) * HID;
    const float4 z4 = make_float4(0.f, 0.f, 0.f, 0.f);

    if (t0 >= seq) {
        // whole tile is padding: zero feature, mask=1, index=0
        #pragma unroll
        for (int tok = 0; tok < TB; ++tok) {
            ((float4*)(rowF + (size_t)tok * HID))[tid] = z4;
        }
        if (tid < TB) {
            int t = t0 + tid;
            outM[b * MAXLEN + t] = 1.0f;
            outI[((size_t)b * MAXLEN + t) * 2 + 0] = 0.f;
            outI[((size_t)b * MAXLEN + t) * 2 + 1] = 0.f;
        }
        return;
    }

    __shared__ float sh_eig[64][TB];   // [j][tok]
    __shared__ int   sh_ids[TB][4];
    __shared__ int   sh_i0[TB], sh_i1[TB], sh_gA[TB], sh_gB[TB];

    // ---- phase 0: token metadata (one thread per token) ----
    if (tid < TB) {
        int t = t0 + tid;
        int i0 = 0, i1 = 0, gA = -1, gB = -1;
        int id0 = 0, id1 = 0, id2 = 0, id3 = 0;
        if (t < seq) {
            if (t < nn) {               // node token
                int g = ns + t;
                i0 = t; i1 = t; gA = g; gB = g;
                id0 = node_data[g * 4 + 0];
                id1 = node_data[g * 4 + 1];
                id2 = node_data[g * 4 + 2];
                id3 = node_data[g * 4 + 3];
            } else {                    // edge token
                int ge = es + (t - nn);
                i0 = edge_index[ge];
                i1 = edge_index[E + ge];
                gA = ns + i0; gB = ns + i1;
                id0 = edge_data[ge * 4 + 0];
                id1 = edge_data[ge * 4 + 1];
                id2 = edge_data[ge * 4 + 2];
                id3 = edge_data[ge * 4 + 3];
            }
        }
        sh_i0[tid] = i0; sh_i1[tid] = i1;
        sh_gA[tid] = gA; sh_gB[tid] = gB;
        sh_ids[tid][0] = id0; sh_ids[tid][1] = id1;
        sh_ids[tid][2] = id2; sh_ids[tid][3] = id3;
    }
    __syncthreads();

    // ---- phase 1: stage eig pairs into LDS [j][tok] (first 128 threads, 8 j's each) ----
    if (tid < 128) {
        int tok   = tid >> 3;           // 0..15
        int jbase = (tid & 7) * 8;      // 0..56
        int gA = sh_gA[tok], gB = sh_gB[tok];
        #pragma unroll
        for (int jj = 0; jj < 8; ++jj) {
            int j = jbase + jj;
            float v = 0.f;
            if (j < 32) { if (gA >= 0) v = eig[(size_t)gA * 32 + j]; }
            else        { if (gB >= 0) v = eig[(size_t)gB * 32 + (j - 32)]; }
            sh_eig[j][tok] = v;
        }
    }
    __syncthreads();

    // ---- phase 2: lap projection. acc[tok] = float4 over this thread's col group ----
    float4 acc[TB];
    #pragma unroll
    for (int i = 0; i < TB; ++i) acc[i] = z4;

    for (int j = 0; j < 64; ++j) {
        float4 w = ((const float4*)(lapW + j * HID))[tid];
        const float4* ev = (const float4*)(&sh_eig[j][0]);
        #pragma unroll
        for (int q = 0; q < TB / 4; ++q) {
            float4 e4 = ev[q];
            acc[q*4+0].x += e4.x * w.x; acc[q*4+0].y += e4.x * w.y;
            acc[q*4+0].z += e4.x * w.z; acc[q*4+0].w += e4.x * w.w;
            acc[q*4+1].x += e4.y * w.x; acc[q*4+1].y += e4.y * w.y;
            acc[q*4+1].z += e4.y * w.z; acc[q*4+1].w += e4.y * w.w;
            acc[q*4+2].x += e4.z * w.x; acc[q*4+2].y += e4.z * w.y;
            acc[q*4+2].z += e4.z * w.z; acc[q*4+2].w += e4.z * w.w;
            acc[q*4+3].x += e4.w * w.x; acc[q*4+3].y += e4.w * w.y;
            acc[q*4+3].z += e4.w * w.z; acc[q*4+3].w += e4.w * w.w;
        }
    }

    // ---- phase 3: embedding gather-sum (float4) + order + store ----
    #pragma unroll
    for (int tok = 0; tok < TB; ++tok) {
        int t = t0 + tok;
        float4* dst = (float4*)(rowF + (size_t)tok * HID) + tid;
        if (t >= seq) { *dst = z4; continue; }
        float4 s = acc[tok];
        #pragma unroll
        for (int r = 0; r < 4; ++r) {
            float4 e = ((const float4*)(embedW + (size_t)sh_ids[tok][r] * HID))[tid];
            s.x += e.x; s.y += e.y; s.z += e.z; s.w += e.w;
        }
        int ord = (sh_i0[tok] == sh_i1[tok]) ? 1 : 0;
        float4 o = ((const float4*)(orderW + (size_t)ord * HID))[tid];
        s.x += o.x; s.y += o.y; s.z += o.z; s.w += o.w;
        *dst = s;
    }

    if (tid < TB) {
        int t = t0 + tid;
        bool pad = (t >= seq);
        outM[b * MAXLEN + t] = pad ? 1.0f : 0.0f;
        outI[((size_t)b * MAXLEN + t) * 2 + 0] = pad ? 0.f : (float)sh_i0[tid];
        outI[((size_t)b * MAXLEN + t) * 2 + 1] = pad ? 0.f : (float)sh_i1[tid];
    }
}

extern "C" void kernel_launch(void* const* d_in, const int* in_sizes, int n_in,
                              void* d_out, int out_size, void* d_ws, size_t ws_size,
                              hipStream_t stream) {
    const float* embedW     = (const float*)d_in[0];
    const float* lapW       = (const float*)d_in[1];
    const float* orderW     = (const float*)d_in[2];
    const float* eig        = (const float*)d_in[3];
    const int*   node_data  = (const int*)d_in[4];
    const int*   edge_data  = (const int*)d_in[5];
    const int*   edge_index = (const int*)d_in[6];
    const int*   node_num   = (const int*)d_in[7];
    const int*   edge_num   = (const int*)d_in[8];
    const int E = in_sizes[6] / 2;

    float* outF = (float*)d_out;
    float* outM = outF + (size_t)BGRAPH * MAXLEN * HID;
    float* outI = outM + (size_t)BGRAPH * MAXLEN;

    dim3 grid(MAXLEN / TB, BGRAPH);
    gft_kernel<<<grid, BLOCK, 0, stream>>>(embedW, lapW, orderW, eig,
                                           node_data, edge_data, edge_index,
                                           node_num, edge_num, E,
                                           outF, outM, outI);
}